// Round 8
// baseline (1933.584 us; speedup 1.0000x reference)
//
#include <hip/hip_runtime.h>
#include <hip/hip_fp16.h>

// ---------------------------------------------------------------------------
// 4-layer GRU stack (Keras reset_after), B=128, T=384, U=D=256.
// 256 persistent blocks = 4 layers x 8 chunks(16 rows) x 8 unit-slices(32 u).
// blockIdx decode puts ALL 32 blocks of a chunk (4 layers x 8 slices) on one
// XCD (blockIdx%8 = XCD round-robin heuristic): c=blk&7, s=(blk>>3)&7.
// Weight B-fragments in REGISTERS. Per step: M=16,N=96,K=512 fp16 MFMA.
// Cross-block h exchange: epoch-tagged 8-byte words ({epoch|h1|h0}) in a
// 16-deep ring. Producers: relaxed SYSTEM-scope stores (write-through to MALL
// -> correct under ANY placement). Consumers: relaxed AGENT-scope loads
// (same-XCD L2 hit when the heuristic holds) with sticky fallback to SYSTEM
// scope after 64 failed validate rounds (placement-independent correctness).
// Joint x+h validate at step start (prefetched at prior step end); 2 barriers
// per step. A in padded fragment order: kt-pitch 69 granules, q-pitch 17
// (staging-write bank-quads = (5ktx+qq+grow)%8 -> conflict-free-ish).
// ---------------------------------------------------------------------------

#define LAYERS 4
#define TSTEPS 384
#define NCH    8
#define WPL    (48 * 16 * 64 * 8)  // repacked weight elems per layer
#define TILE_STRIDE (16 * 64 * 8)  // 8192 elems per 16-col tile
#define RING   16
#define SLOT_ULL (16 * 128)        // 16 rows x 128 tagged ulls per slot
#define GRP_ULL  (RING * SLOT_ULL)
#define KP 552                     // halves per kt-row   (69 granules of 16B)
#define QP 136                     // halves per q-group  (17 granules)

typedef _Float16 half8 __attribute__((ext_vector_type(8)));
typedef float    f32x4 __attribute__((ext_vector_type(4)));
typedef unsigned uint4v __attribute__((ext_vector_type(4)));
typedef unsigned long long ull;

// ws layout (bytes)
#define WP_OFF   0
#define BP_OFF   (LAYERS * WPL * 2)                 // 3,145,728
#define FLAG_OFF (BP_OFF + LAYERS * 1024 * 4)       // +16 KB
#define FLAG_BYTES 4096
#define HBUF_OFF (4 * 1024 * 1024)

// ---------------------------------------------------------------------------
// Repack: W[l] -> [tile=48][kt=16][lane=64][8] fp16 B-fragments.
// n = tile*16 + (lane&15), k = kt*32 + (lane>>4)*8 + j.
// Bias: [0:512]=b_in+b_rec (z,r), [512:768]=b_in_h, [768:1024]=b_rec_h.
// ---------------------------------------------------------------------------
__global__ void repack_kernel(const float* __restrict__ k0, const float* __restrict__ rk0,
                              const float* __restrict__ b0, const float* __restrict__ kern,
                              const float* __restrict__ rkern, const float* __restrict__ bias,
                              _Float16* __restrict__ Wp, float* __restrict__ Bp)
{
    int idx = blockIdx.x * 256 + threadIdx.x;
    const int total_w = LAYERS * WPL;
    if (idx < total_w) {
        int l = idx / WPL;
        int r = idx - l * WPL;
        int j    = r & 7;
        int lane = (r >> 3) & 63;
        int kt   = (r >> 9) & 15;
        int tile = r >> 13;
        int n = tile * 16 + (lane & 15);
        int k = kt * 32 + (lane >> 4) * 8 + j;
        float v;
        if (l == 0) {
            v = (k < 256) ? k0[(size_t)k * 768 + n] : rk0[(size_t)(k - 256) * 768 + n];
        } else {
            const float* kk = kern  + (size_t)(l - 1) * 256 * 768;
            const float* rk = rkern + (size_t)(l - 1) * 256 * 768;
            v = (k < 256) ? kk[(size_t)k * 768 + n] : rk[(size_t)(k - 256) * 768 + n];
        }
        Wp[idx] = (_Float16)v;
    } else {
        int ib = idx - total_w;
        if (ib < LAYERS * 1024) {
            int l = ib >> 10;
            int i = ib & 1023;
            const float* bs = (l == 0) ? b0 : (bias + (size_t)(l - 1) * 2 * 768);
            float v;
            if (i < 512)      v = bs[i] + bs[768 + i];
            else if (i < 768) v = bs[512 + (i - 512)];
            else              v = bs[768 + 512 + (i - 768)];
            Bp[l * 1024 + i] = v;
        }
    }
}

// ---------------------------------------------------------------------------
// Persistent GRU kernel: 384 threads = 6 waves; wave w computes one 16-col
// tile: w0,w1=z  w2,w3=r  w4,w5=h (split accumulators k<256 / k>=256).
// ---------------------------------------------------------------------------
__launch_bounds__(384, 1)
__global__ void gru_kernel(const float* __restrict__ x,
                           const _Float16* __restrict__ Wp,
                           const float* __restrict__ Bp,
                           ull* __restrict__ hbuf,
                           unsigned int* __restrict__ flags,
                           float* __restrict__ out)
{
    __shared__ _Float16 Af[16 * KP];       // padded fragment-ordered A, 17.7 KB
    __shared__ float    Sc[8][16][17];     // 8.7 KB

    const int tid  = threadIdx.x;
    const int lane = tid & 63;
    const int w    = tid >> 6;
    const int lo16 = lane & 15;
    const int q    = lane >> 4;

    const int c = blockIdx.x & 7;          // batch chunk == XCD (heuristic)
    const int s = (blockIdx.x >> 3) & 7;   // unit slice
    const int l = blockIdx.x >> 6;         // layer
    const int b0row = c * 16;

    // ---- this wave's weight tile -> registers (once) ----
    const int tile = (w >> 1) * 16 + 2 * s + (w & 1);
    half8 bfrag[16];
    {
        const _Float16* wb = Wp + (size_t)l * WPL + (size_t)tile * TILE_STRIDE;
#pragma unroll
        for (int kt = 0; kt < 16; ++kt)
            bfrag[kt] = *(const half8*)(wb + ((size_t)kt * 64 + lane) * 8);
    }

    // ---- per-gate-thread mapping (tid<256: row grow, units gup,gup+1) ----
    const int grow = tid >> 4;
    const int g16  = tid & 15;
    const int gup  = g16 * 2;
    const int ktx  = g16 >> 1;
    const int qq   = (g16 & 1) * 2;
    const int xoff0 = ktx * KP + qq * QP + grow * 8;
    const int xoff1 = ktx * KP + (qq + 1) * QP + grow * 8;
    const int hoff0 = (8 + ktx) * KP + qq * QP + grow * 8;
    const int hoff1 = (8 + ktx) * KP + (qq + 1) * QP + grow * 8;

    float bz[2] = {0,0}, br[2] = {0,0}, bi[2] = {0,0}, bh[2] = {0,0};
    float hprev[2] = {0.f, 0.f};
    if (tid < 256) {
        const float* bp = Bp + l * 1024;
        int ug = s * 32 + gup;
        bz[0] = bp[ug];       bz[1] = bp[ug + 1];
        br[0] = bp[256 + ug]; br[1] = bp[256 + ug + 1];
        bi[0] = bp[512 + ug]; bi[1] = bp[512 + ug + 1];
        bh[0] = bp[768 + ug]; bh[1] = bp[768 + ug + 1];
    }

    unsigned int* fl_own_g = flags + (l * NCH + c) * 16;
    unsigned int* fl_dn_g  = flags + ((l < 3 ? l + 1 : 0) * NCH + c) * 16;
    unsigned int* my_flag  = fl_own_g + s;

    ull*       hb_own = hbuf + (size_t)(l * NCH + c) * GRP_ULL;
    const ull* hb_up  = hbuf + (size_t)((l > 0 ? l - 1 : 0) * NCH + c) * GRP_ULL;

    auto wait_group = [&](const unsigned int* base, unsigned need) {
        for (;;) {
            unsigned v = 0xFFFFFFFFu;
            if (lane < 8)
                v = __hip_atomic_load(base + lane, __ATOMIC_RELAXED,
                                      __HIP_MEMORY_SCOPE_SYSTEM);
            if (__all((int)(v >= need))) return;
            __builtin_amdgcn_s_sleep(1);
        }
    };

    ull   vx[8], vh[8];
    f32x4 px0, px1, px2, px3;
    int   fb = 0;   // sticky fallback: agent-scope -> system-scope loads

    // ---- prologue: prefetch inputs for t=0 ----
    if (tid < 256) {
        if (l == 0) {
            const float* sp = x + ((size_t)(b0row + grow) * TSTEPS + 0) * 256 + gup * 8;
            px0 = *(const f32x4*)sp;       px1 = *(const f32x4*)(sp + 4);
            px2 = *(const f32x4*)(sp + 8); px3 = *(const f32x4*)(sp + 12);
        } else {
            const ull* spx = hb_up + (size_t)0 * SLOT_ULL + grow * 128 + g16 * 8;
#pragma unroll
            for (int j = 0; j < 8; ++j)
                vx[j] = __hip_atomic_load(spx + j, __ATOMIC_RELAXED, __HIP_MEMORY_SCOPE_AGENT);
        }
    }

    for (int t = 0; t < TSTEPS; ++t) {
        // ---- stage 1: joint validate (x(t) + own h(t-1)), stage A ----
        if (tid < 256) {
            const ull* spx = hb_up  + (size_t)(t & (RING - 1)) * SLOT_ULL + grow * 128 + g16 * 8;
            const ull* sph = hb_own + (size_t)((t - 1) & (RING - 1)) * SLOT_ULL + grow * 128 + g16 * 8;
            const unsigned xt = (unsigned)(t + 1);
            const unsigned ht = (unsigned)t;
            if (l > 0 || t > 0) {
                int rounds = 0;
                for (;;) {
                    bool ok = true;
                    if (l > 0) {
#pragma unroll
                        for (int j = 0; j < 8; ++j)
                            if ((unsigned)(vx[j] >> 32) != xt) {
                                vx[j] = fb ? __hip_atomic_load(spx + j, __ATOMIC_RELAXED, __HIP_MEMORY_SCOPE_SYSTEM)
                                           : __hip_atomic_load(spx + j, __ATOMIC_RELAXED, __HIP_MEMORY_SCOPE_AGENT);
                                ok = false;
                            }
                    }
                    if (t > 0) {
#pragma unroll
                        for (int j = 0; j < 8; ++j)
                            if ((unsigned)(vh[j] >> 32) != ht) {
                                vh[j] = fb ? __hip_atomic_load(sph + j, __ATOMIC_RELAXED, __HIP_MEMORY_SCOPE_SYSTEM)
                                           : __hip_atomic_load(sph + j, __ATOMIC_RELAXED, __HIP_MEMORY_SCOPE_AGENT);
                                ok = false;
                            }
                    }
                    if (ok) break;
                    if (++rounds >= 64) fb = 1;
                }
            }
            // stage x-half
            if (l == 0) {
                half8 h0, h1;
                h0[0]=(_Float16)px0[0]; h0[1]=(_Float16)px0[1]; h0[2]=(_Float16)px0[2]; h0[3]=(_Float16)px0[3];
                h0[4]=(_Float16)px1[0]; h0[5]=(_Float16)px1[1]; h0[6]=(_Float16)px1[2]; h0[7]=(_Float16)px1[3];
                h1[0]=(_Float16)px2[0]; h1[1]=(_Float16)px2[1]; h1[2]=(_Float16)px2[2]; h1[3]=(_Float16)px2[3];
                h1[4]=(_Float16)px3[0]; h1[5]=(_Float16)px3[1]; h1[6]=(_Float16)px3[2]; h1[7]=(_Float16)px3[3];
                *(half8*)(Af + xoff0) = h0;
                *(half8*)(Af + xoff1) = h1;
            } else {
                uint4v w0, w1;
                w0[0]=(unsigned)vx[0]; w0[1]=(unsigned)vx[1]; w0[2]=(unsigned)vx[2]; w0[3]=(unsigned)vx[3];
                w1[0]=(unsigned)vx[4]; w1[1]=(unsigned)vx[5]; w1[2]=(unsigned)vx[6]; w1[3]=(unsigned)vx[7];
                *(uint4v*)(Af + xoff0) = w0;
                *(uint4v*)(Af + xoff1) = w1;
            }
            // stage h-half
            if (t > 0) {
                uint4v w0, w1;
                w0[0]=(unsigned)vh[0]; w0[1]=(unsigned)vh[1]; w0[2]=(unsigned)vh[2]; w0[3]=(unsigned)vh[3];
                w1[0]=(unsigned)vh[4]; w1[1]=(unsigned)vh[5]; w1[2]=(unsigned)vh[6]; w1[3]=(unsigned)vh[7];
                *(uint4v*)(Af + hoff0) = w0;
                *(uint4v*)(Af + hoff1) = w1;
            } else {
                uint4v z = {0u, 0u, 0u, 0u};
                *(uint4v*)(Af + hoff0) = z;
                *(uint4v*)(Af + hoff1) = z;
            }
        }
        __syncthreads();   // B1: A complete

        // ---- stage 2: MFMA (a-frag = contiguous ds_read_b128, padded rows) ----
        f32x4 acc0 = {0,0,0,0}, acc1 = {0,0,0,0};
#pragma unroll
        for (int kt = 0; kt < 16; ++kt) {
            half8 a = *(const half8*)(Af + kt * KP + q * QP + lo16 * 8);
            if (w < 4 || kt < 8)
                acc0 = __builtin_amdgcn_mfma_f32_16x16x32_f16(a, bfrag[kt], acc0, 0, 0, 0);
            else
                acc1 = __builtin_amdgcn_mfma_f32_16x16x32_f16(a, bfrag[kt], acc1, 0, 0, 0);
        }
#pragma unroll
        for (int r = 0; r < 4; ++r) Sc[w][q * 4 + r][lo16] = acc0[r];
        if (w >= 4) {
#pragma unroll
            for (int r = 0; r < 4; ++r) Sc[w + 2][q * 4 + r][lo16] = acc1[r];
        }
        __syncthreads();   // B2: Sc complete; all step-t input consumption done

        // consumption flag (backpressure for upstream) — publish early
        if (tid == 0)
            __hip_atomic_store(my_flag, (unsigned)(t + 1),
                               __ATOMIC_RELAXED, __HIP_MEMORY_SCOPE_SYSTEM);

        // ring backpressure before overwriting own slot t
        if (l < 3 && t >= RING) wait_group(fl_dn_g, (unsigned)(t - RING + 1));

        // ---- gates; publish tagged h(t) ----
        if (tid < 256) {
            float hn[2];
#pragma unroll
            for (int j = 0; j < 2; ++j) {
                int u   = gup + j;
                int ut  = u >> 4;
                int col = u & 15;
                float zp = Sc[ut][grow][col]     + bz[j];
                float rp = Sc[2 + ut][grow][col] + br[j];
                float ip = Sc[4 + ut][grow][col] + bi[j];
                float hp = Sc[6 + ut][grow][col] + bh[j];
                float z  = 1.f / (1.f + __expf(-zp));
                float rr = 1.f / (1.f + __expf(-rp));
                float pre = ip + rr * hp;
                float e  = __expf(2.f * pre);
                float th = 1.f - 2.f / (e + 1.f);
                hn[j] = z * hprev[j] + (1.f - z) * th;
                hprev[j] = hn[j];
            }
            union { _Float16 h[2]; unsigned u32; } pk;
            pk.h[0] = (_Float16)hn[0];
            pk.h[1] = (_Float16)hn[1];
            ull word = ((ull)(unsigned)(t + 1) << 32) | (ull)pk.u32;
            __hip_atomic_store(hb_own + (size_t)(t & (RING - 1)) * SLOT_ULL + grow * 128 + s * 16 + g16,
                               word, __ATOMIC_RELAXED, __HIP_MEMORY_SCOPE_SYSTEM);
            if (l == 3 && t == TSTEPS - 1) {
                float* op = out + (size_t)(b0row + grow) * 256 + s * 32 + gup;
                op[0] = hn[0];
                op[1] = hn[1];
            }
        }

        // ---- prefetch inputs for t+1 (registers only; validated next step) ----
        if (t + 1 < TSTEPS && tid < 256) {
            if (l == 0) {
                const float* sp = x + ((size_t)(b0row + grow) * TSTEPS + (t + 1)) * 256 + gup * 8;
                px0 = *(const f32x4*)sp;       px1 = *(const f32x4*)(sp + 4);
                px2 = *(const f32x4*)(sp + 8); px3 = *(const f32x4*)(sp + 12);
            } else {
                const ull* spx = hb_up + (size_t)((t + 1) & (RING - 1)) * SLOT_ULL + grow * 128 + g16 * 8;
#pragma unroll
                for (int j = 0; j < 8; ++j)
                    vx[j] = __hip_atomic_load(spx + j, __ATOMIC_RELAXED, __HIP_MEMORY_SCOPE_AGENT);
            }
            const ull* sph = hb_own + (size_t)(t & (RING - 1)) * SLOT_ULL + grow * 128 + g16 * 8;
#pragma unroll
            for (int j = 0; j < 8; ++j)
                vh[j] = __hip_atomic_load(sph + j, __ATOMIC_RELAXED, __HIP_MEMORY_SCOPE_AGENT);
        }
        // no B3: B1 of step t+1 orders stage-1 A-writes after this step's reads
    }
}

extern "C" void kernel_launch(void* const* d_in, const int* in_sizes, int n_in,
                              void* d_out, int out_size, void* d_ws, size_t ws_size,
                              hipStream_t stream)
{
    const float* x     = (const float*)d_in[0];
    const float* k0    = (const float*)d_in[1];
    const float* rk0   = (const float*)d_in[2];
    const float* b0    = (const float*)d_in[3];
    const float* kern  = (const float*)d_in[4];
    const float* rkern = (const float*)d_in[5];
    const float* bias  = (const float*)d_in[6];
    float* out = (float*)d_out;

    char* ws = (char*)d_ws;
    _Float16*     Wp    = (_Float16*)(ws + WP_OFF);
    float*        Bp    = (float*)(ws + BP_OFF);
    unsigned int* flags = (unsigned int*)(ws + FLAG_OFF);
    ull*          hbuf  = (ull*)(ws + HBUF_OFF);

    hipMemsetAsync(flags, 0, FLAG_BYTES, stream);

    const int total = LAYERS * WPL + LAYERS * 1024;
    repack_kernel<<<(total + 255) / 256, 256, 0, stream>>>(k0, rk0, b0, kern, rkern, bias, Wp, Bp);

    gru_kernel<<<LAYERS * NCH * 8, 384, 0, stream>>>(x, Wp, Bp, hbuf, flags, out);
}